// Round 1
// baseline (112.265 us; speedup 1.0000x reference)
//
#include <hip/hip_runtime.h>
#include <math.h>

// S4 diagonal SSM: B=2, L=2048, H=512, N=64. Chunked: T=32, NC=64.
//   y[cT+t'] = sum_{tau<=t'} K[h,tau]*u[t-tau] + sum_n C[n]*Ad^(t'+1)*S_c[b,n,h]
//   K[h,tau] = sum_n C[n]*Bd[h,n]*Ad[h,n]^tau  (D folded into K[0])
// R7 theory: previous T=64 structure ran 512-block kernels (2 waves/SIMD) and a
// 256-block scan (1 wave/SIMD) -- latency-bound, 5x above VALU+HBM rooflines.
// T=32 doubles grid to 1024 blocks (4 waves/SIMD), halves serial depth, and
// slightly cuts k_out FLOPs/output. XCD-bijective swizzle co-locates the 8
// blocks sharing a u-chunk / S-panel on one XCD L2.
// Lessons baked in: (R4) cooperative grid.sync ~70us/sync -- never fuse that way;
// (R6) packing state tables fat costs HBM/L2 bytes -- keep scalar S-table +
// small L1-resident Ad/Cp tables.

#define BATCH   2
#define SEQLEN  2048
#define DMODEL  512
#define DSTATE  64
#define T_CHUNK 32
#define NCHUNK  64
#define RT      8

__device__ __forceinline__ float A_cont(int n) {
    // A[n] = (1 + (n+1)/64)^(-1/2)
    return rsqrtf(1.0f + (float)(n + 1) * (1.0f / 64.0f));
}

// ---------------- Kernel 1: xlocal[b][c][n][h] (16 states/thread) ----------------
__global__ __launch_bounds__(256) void k_xlocal(const float* __restrict__ u,
                                                const float* __restrict__ B_re,
                                                const float* __restrict__ log_dt,
                                                float* __restrict__ xl) {
    int bid = (int)blockIdx.x;                     // 1024 blocks
    int wb  = (bid & 7) * 128 + (bid >> 3);        // XCD-contiguous work order
    int tid = wb * 256 + (int)threadIdx.x;         // 262144 threads
    int h  = tid & (DMODEL - 1);
    int ng = (tid >> 9) & 3;                       // 16 n per group
    int c  = (tid >> 11) & (NCHUNK - 1);
    int b  = tid >> 17;
    float delta = expf(log_dt[h]);
    float Ad[16], Bd[16], x[16];
    #pragma unroll
    for (int nn = 0; nn < 16; ++nn) {
        int n = ng * 16 + nn;
        float dA = delta * A_cont(n);
        Ad[nn] = expf(dA);
        Bd[nn] = expm1f(dA) * B_re[n] * delta;
        x[nn] = 0.0f;
    }
    const float* up = u + ((size_t)(b * SEQLEN + c * T_CHUNK)) * DMODEL + h;
    #pragma unroll 8
    for (int s = 0; s < T_CHUNK; ++s) {
        float uv = up[(size_t)s * DMODEL];         // coalesced in h
        #pragma unroll
        for (int nn = 0; nn < 16; ++nn)
            x[nn] = fmaf(Ad[nn], x[nn], Bd[nn] * uv);
    }
    float* xp = xl + ((size_t)((b * NCHUNK + c) * DSTATE + ng * 16)) * DMODEL + h;
    #pragma unroll
    for (int nn = 0; nn < 16; ++nn) xp[(size_t)nn * DMODEL] = x[nn];
}

// ---------------- Kernel 2: chunk scan (unrolled) + table setup ----------------
// Scan: after this, xl[b][c-1][n][h] holds S_c (state entering chunk c).
// Setup (tid<32768): AdTab[64][512], CpStep[4][64][512] = C*Ad^(8i+1);
//        (tid<16384): Kbuf[32][512] (D folded at tau=0).
__global__ __launch_bounds__(256) void k_scanset(const float* __restrict__ B_re,
                                                 const float* __restrict__ C_re,
                                                 const float* __restrict__ log_dt,
                                                 const float* __restrict__ Dp,
                                                 float* __restrict__ xl,
                                                 float* __restrict__ Kbuf,
                                                 float* __restrict__ AdTab,
                                                 float* __restrict__ CpStep) {
    int tid = blockIdx.x * 256 + threadIdx.x;      // 65536 threads
    {
        int h = tid & (DMODEL - 1);
        int n = (tid >> 9) & (DSTATE - 1);
        int b = tid >> 15;
        float delta = expf(log_dt[h]);
        float ApT = expf(delta * A_cont(n) * (float)T_CHUNK);  // Ad^T
        float* base = xl + ((size_t)(b * NCHUNK * DSTATE + n)) * DMODEL + h;
        float v[NCHUNK - 1];
        #pragma unroll
        for (int c = 0; c < NCHUNK - 1; ++c)
            v[c] = base[(size_t)c * DSTATE * DMODEL];          // 63 independent loads
        float s = 0.0f;
        #pragma unroll
        for (int c = 0; c < NCHUNK - 1; ++c) { s = fmaf(ApT, s, v[c]); v[c] = s; }
        #pragma unroll
        for (int c = 0; c < NCHUNK - 1; ++c)
            base[(size_t)c * DSTATE * DMODEL] = v[c];
    }
    if (tid < 32768) {
        int h = tid & (DMODEL - 1);
        int n = tid >> 9;                          // 0..63
        float delta = expf(log_dt[h]);
        float Adn = expf(delta * A_cont(n));
        AdTab[n * DMODEL + h] = Adn;
        float sq = Adn * Adn; sq = sq * sq;        // Adn^4
        float e8 = sq * sq;                        // Adn^8
        float p = C_re[n] * Adn;                   // C*Ad^1
        #pragma unroll
        for (int i = 0; i < 4; ++i) {
            CpStep[(i * DSTATE + n) * DMODEL + h] = p;
            p *= e8;
        }
        if (n < T_CHUNK) {                         // Kbuf row j = n (0..31)
            int j = n;
            float acc = (j == 0) ? Dp[h] : 0.0f;   // D folded into K[0]
            for (int nn = 0; nn < DSTATE; ++nn) {
                float dAn = delta * A_cont(nn);
                float Bdv = expm1f(dAn) * B_re[nn] * delta;
                acc = fmaf(C_re[nn] * Bdv, expf(dAn * (float)j), acc);
            }
            Kbuf[j * DMODEL + h] = acc;
        }
    }
}

// ---------------- Kernel 3: output, 8 t' per thread, 8x8 block conv ----------------
__global__ __launch_bounds__(256) void k_out(const float* __restrict__ u,
                                             const float* __restrict__ Kbuf,
                                             const float* __restrict__ AdTab,
                                             const float* __restrict__ CpStep,
                                             const float* __restrict__ Sbuf,
                                             float* __restrict__ out) {
    int bid = (int)blockIdx.x;                     // 1024 blocks
    int wb  = (bid & 7) * 128 + (bid >> 3);        // XCD-contiguous work order
    int tid = wb * 256 + (int)threadIdx.x;         // 262144 threads
    int h   = tid & (DMODEL - 1);
    int it  = (tid >> 9) & 3;                      // t'-tile of 8 (block-uniform)
    int c   = (tid >> 11) & (NCHUNK - 1);
    int b   = tid >> 17;
    int tp0 = it * RT;

    const float* ub = u + ((size_t)(b * SEQLEN + c * T_CHUNK)) * DMODEL + h;
    const float* kb = Kbuf + h;

    float acc[RT];
    #pragma unroll
    for (int i = 0; i < RT; ++i) acc[i] = 0.0f;

    // full 8x8 source blocks: 23 loads -> 64 FMA each (compile-time indices)
    for (int sb = 0; sb < it; ++sb) {
        float ureg[8], krow[15];
        int base = tp0 - sb * 8 - 7;               // >= 1
        #pragma unroll
        for (int q = 0; q < 8; ++q) ureg[q] = ub[(size_t)(sb * 8 + q) * DMODEL];
        #pragma unroll
        for (int j = 0; j < 15; ++j) krow[j] = kb[(size_t)(base + j) * DMODEL];
        #pragma unroll
        for (int q = 0; q < 8; ++q)
            #pragma unroll
            for (int i = 0; i < RT; ++i)
                acc[i] = fmaf(krow[i - q + 7], ureg[q], acc[i]);   // K[tp0+i-(sb*8+q)]
    }
    // diagonal (causal) block: 16 loads -> 36 FMA
    {
        float ureg[8], krow[8];
        #pragma unroll
        for (int q = 0; q < 8; ++q) ureg[q] = ub[(size_t)(tp0 + q) * DMODEL];
        #pragma unroll
        for (int j = 0; j < 8; ++j) krow[j] = kb[(size_t)j * DMODEL];
        #pragma unroll
        for (int q = 0; q < 8; ++q)
            #pragma unroll
            for (int i = 0; i < RT; ++i)
                if (i >= q) acc[i] = fmaf(krow[i - q], ureg[q], acc[i]);
    }
    // chunk-entry-state correction: acc[i] += sum_n C*Ad^(tp0+i+1) * S[n]
    if (c > 0) {
        const float* sp = Sbuf + ((size_t)((b * NCHUNK + (c - 1)) * DSTATE)) * DMODEL + h;
        const float* ap = AdTab + h;
        const float* cp = CpStep + (size_t)(it * DSTATE) * DMODEL + h;
        #pragma unroll 4
        for (int n = 0; n < DSTATE; ++n) {
            float Sv  = sp[(size_t)n * DMODEL];
            float Adv = ap[(size_t)n * DMODEL];
            float w   = cp[(size_t)n * DMODEL] * Sv;
            acc[0] += w;
            #pragma unroll
            for (int i = 1; i < RT; ++i) { w *= Adv; acc[i] += w; }
        }
    }
    float* ob = out + ((size_t)(b * SEQLEN + c * T_CHUNK + tp0)) * DMODEL + h;
    #pragma unroll
    for (int i = 0; i < RT; ++i)
        __builtin_nontemporal_store(acc[i], &ob[(size_t)i * DMODEL]);  // out never re-read in-window
}

extern "C" void kernel_launch(void* const* d_in, const int* in_sizes, int n_in,
                              void* d_out, int out_size, void* d_ws, size_t ws_size,
                              hipStream_t stream) {
    const float* u      = (const float*)d_in[0];
    const float* B_re   = (const float*)d_in[1];
    const float* C_re   = (const float*)d_in[2];
    const float* log_dt = (const float*)d_in[3];
    const float* D      = (const float*)d_in[4];
    float* out = (float*)d_out;
    float* ws  = (float*)d_ws;

    // ws layout (floats):
    float* Kbuf   = ws;                            // 32*512   = 16384
    float* AdTab  = ws + 16384;                    // 64*512   = 32768
    float* CpStep = ws + 49152;                    // 4*64*512 = 131072
    float* xl     = ws + 180224;                   // 2*64*64*512 = 4194304

    k_xlocal <<<1024, 256, 0, stream>>>(u, B_re, log_dt, xl);
    k_scanset<<<256, 256, 0, stream>>>(B_re, C_re, log_dt, D, xl, Kbuf, AdTab, CpStep);
    k_out    <<<1024, 256, 0, stream>>>(u, Kbuf, AdTab, CpStep, xl, out);
}

// Round 3
// 110.059 us; speedup vs baseline: 1.0200x; 1.0200x over previous
//
#include <hip/hip_runtime.h>
#include <math.h>

// S4 diagonal SSM: B=2, L=2048, H=512, N=64. Chunked state-domain: T=32, NC=64.
// R8 rewrite: drop the kernel-convolution formulation (k_out had ~1100 VALU/thread
// in the correction loop + 7-deep serial mul chains + Kbuf/CpStep machinery).
// Instead: phase1 local end-states (table-driven), phase2 chunk scan, phase3
// re-run the exact recurrence with carry as init state, y = C.x + D.u, with the
// 64-state dot split across 4 lane-groups (16 n each) + two __shfl_xor reduces.
// All expf/expm1f moved to a one-shot table kernel (Ad/Bd [n][h], 256 KB, L2-hot).
// Lessons: (R4) coop grid.sync ~70us -- never; (R6) fat tables cost HBM; (R7)
// occupancy 2->4 waves/SIMD alone changed nothing -- cut instructions instead.
// (R9: identical resubmit -- R8 bench died to container infra, no data.)

#define BATCH   2
#define SEQLEN  2048
#define DMODEL  512
#define DSTATE  64
#define T_CHUNK 32
#define NCHUNK  64

__device__ __forceinline__ float A_cont(int n) {
    // A[n] = (1 + (n+1)/64)^(-1/2)
    return rsqrtf(1.0f + (float)(n + 1) * (1.0f / 64.0f));
}

// ---------------- Kernel 0: coefficient tables Ad[n][h], Bd[n][h] ----------------
__global__ __launch_bounds__(256) void k_tables(const float* __restrict__ B_re,
                                                const float* __restrict__ log_dt,
                                                float* __restrict__ AdT,
                                                float* __restrict__ BdT) {
    int tid = blockIdx.x * 256 + threadIdx.x;      // 32768 threads
    int h = tid & (DMODEL - 1);
    int n = tid >> 9;                              // 0..63
    float delta = expf(log_dt[h]);
    float dA = delta * A_cont(n);
    AdT[n * DMODEL + h] = expf(dA);
    BdT[n * DMODEL + h] = expm1f(dA) * B_re[n] * delta;
}

// ---------------- Kernel 1: local chunk end-states xl[b][c][n][h] ----------------
__global__ __launch_bounds__(256) void k_xlocal(const float* __restrict__ u,
                                                const float* __restrict__ AdT,
                                                const float* __restrict__ BdT,
                                                float* __restrict__ xl) {
    int bid = (int)blockIdx.x;                     // 1024 blocks
    int wb  = (bid & 7) * 128 + (bid >> 3);        // XCD-contiguous work order
    int tid = wb * 256 + (int)threadIdx.x;         // 262144 threads
    int h  = tid & (DMODEL - 1);
    int ng = (tid >> 9) & 3;                       // 16 n per group
    int c  = (tid >> 11) & (NCHUNK - 1);
    int b  = tid >> 17;
    int n0 = ng * 16;
    float Ad[16], Bd[16], x[16];
    #pragma unroll
    for (int nn = 0; nn < 16; ++nn) {
        Ad[nn] = AdT[(size_t)(n0 + nn) * DMODEL + h];   // 256B coalesced, L2-hot
        Bd[nn] = BdT[(size_t)(n0 + nn) * DMODEL + h];
        x[nn] = 0.0f;
    }
    const float* up = u + ((size_t)(b * SEQLEN + c * T_CHUNK)) * DMODEL + h;
    #pragma unroll 8
    for (int s = 0; s < T_CHUNK; ++s) {
        float uv = up[(size_t)s * DMODEL];
        #pragma unroll
        for (int nn = 0; nn < 16; ++nn)
            x[nn] = fmaf(Ad[nn], x[nn], Bd[nn] * uv);
    }
    float* xp = xl + ((size_t)((b * NCHUNK + c) * DSTATE + n0)) * DMODEL + h;
    #pragma unroll
    for (int nn = 0; nn < 16; ++nn) xp[(size_t)nn * DMODEL] = x[nn];
}

// ---------------- Kernel 2: chunk prefix scan (in place) ----------------
// After: xl[b][c][n][h] = true end state of chunk c (= carry into chunk c+1).
__global__ __launch_bounds__(256) void k_scan(const float* __restrict__ log_dt,
                                              float* __restrict__ xl) {
    int tid = blockIdx.x * 256 + threadIdx.x;      // 65536 threads
    int h = tid & (DMODEL - 1);
    int n = (tid >> 9) & (DSTATE - 1);
    int b = tid >> 15;
    float delta = expf(log_dt[h]);
    float ApT = expf(delta * A_cont(n) * (float)T_CHUNK);  // Ad^T
    float* base = xl + ((size_t)(b * NCHUNK * DSTATE + n)) * DMODEL + h;
    float v[NCHUNK - 1];
    #pragma unroll
    for (int c = 0; c < NCHUNK - 1; ++c)
        v[c] = base[(size_t)c * DSTATE * DMODEL];          // 63 independent loads
    float s = 0.0f;
    #pragma unroll
    for (int c = 0; c < NCHUNK - 1; ++c) { s = fmaf(ApT, s, v[c]); v[c] = s; }
    #pragma unroll
    for (int c = 0; c < NCHUNK - 1; ++c)
        base[(size_t)c * DSTATE * DMODEL] = v[c];
}

// ---------------- Kernel 3: y = C.x + D.u, recurrence re-run with carry ----------------
// Lane layout: lane[3:0]=h[3:0], lane[5:4]=ng. 4 lane-groups each own 16 n;
// dot reduced with __shfl_xor(16) + __shfl_xor(32); lanes 0-15 store.
__global__ __launch_bounds__(256) void k_y(const float* __restrict__ u,
                                           const float* __restrict__ AdT,
                                           const float* __restrict__ BdT,
                                           const float* __restrict__ C_re,
                                           const float* __restrict__ Dp,
                                           const float* __restrict__ Sbuf,
                                           float* __restrict__ out) {
    int bid = (int)blockIdx.x;                     // 1024 blocks
    int wb  = (bid & 7) * 128 + (bid >> 3);        // XCD-contiguous work order
    int tid = wb * 256 + (int)threadIdx.x;
    int hl = tid & 15;                             // h[3:0] (lane bits 0-3)
    int ng = (tid >> 4) & 3;                       // lane bits 4-5
    int hm = (tid >> 6) & 31;                      // h[8:4]
    int h  = hl | (hm << 4);
    int c  = (tid >> 11) & (NCHUNK - 1);
    int b  = tid >> 17;
    int n0 = ng * 16;

    float Ad[16], Bd[16], Cw[16], x[16];
    #pragma unroll
    for (int nn = 0; nn < 16; ++nn) {
        Ad[nn] = AdT[(size_t)(n0 + nn) * DMODEL + h];
        Bd[nn] = BdT[(size_t)(n0 + nn) * DMODEL + h];
        Cw[nn] = C_re[n0 + nn];                    // wave-broadcast
    }
    if (c > 0) {
        const float* sp = Sbuf + ((size_t)((b * NCHUNK + (c - 1)) * DSTATE + n0)) * DMODEL + h;
        #pragma unroll
        for (int nn = 0; nn < 16; ++nn) x[nn] = sp[(size_t)nn * DMODEL];
    } else {
        #pragma unroll
        for (int nn = 0; nn < 16; ++nn) x[nn] = 0.0f;
    }
    float Dv = Dp[h];
    const float* up = u   + ((size_t)(b * SEQLEN + c * T_CHUNK)) * DMODEL + h;
    float*       op = out + ((size_t)(b * SEQLEN + c * T_CHUNK)) * DMODEL + h;
    int store_lane = ((threadIdx.x & 48) == 0);    // lanes 0-15 of each wave

    #pragma unroll 4
    for (int t = 0; t < T_CHUNK; ++t) {
        float uv = up[(size_t)t * DMODEL];
        #pragma unroll
        for (int nn = 0; nn < 16; ++nn)
            x[nn] = fmaf(Ad[nn], x[nn], Bd[nn] * uv);
        // 4-way partial dot (short dep chains), then lane reduce
        float a0 = 0.0f, a1 = 0.0f, a2 = 0.0f, a3 = 0.0f;
        #pragma unroll
        for (int nn = 0; nn < 16; nn += 4) {
            a0 = fmaf(Cw[nn + 0], x[nn + 0], a0);
            a1 = fmaf(Cw[nn + 1], x[nn + 1], a1);
            a2 = fmaf(Cw[nn + 2], x[nn + 2], a2);
            a3 = fmaf(Cw[nn + 3], x[nn + 3], a3);
        }
        float acc = (a0 + a1) + (a2 + a3);
        acc += __shfl_xor(acc, 16);                // combine ng pairs
        acc += __shfl_xor(acc, 32);                // full 64-n sum in all lanes
        if (store_lane)
            __builtin_nontemporal_store(fmaf(Dv, uv, acc), &op[(size_t)t * DMODEL]);
    }
}

extern "C" void kernel_launch(void* const* d_in, const int* in_sizes, int n_in,
                              void* d_out, int out_size, void* d_ws, size_t ws_size,
                              hipStream_t stream) {
    const float* u      = (const float*)d_in[0];
    const float* B_re   = (const float*)d_in[1];
    const float* C_re   = (const float*)d_in[2];
    const float* log_dt = (const float*)d_in[3];
    const float* D      = (const float*)d_in[4];
    float* out = (float*)d_out;
    float* ws  = (float*)d_ws;

    // ws layout (floats):
    float* AdT = ws;                               // 64*512 = 32768
    float* BdT = ws + 32768;                       // 64*512 = 32768
    float* xl  = ws + 65536;                       // 2*64*64*512 = 4194304 (16 MB)

    k_tables<<<128,  256, 0, stream>>>(B_re, log_dt, AdT, BdT);
    k_xlocal<<<1024, 256, 0, stream>>>(u, AdT, BdT, xl);
    k_scan  <<<256,  256, 0, stream>>>(log_dt, xl);
    k_y     <<<1024, 256, 0, stream>>>(u, AdT, BdT, C_re, D, xl, out);
}

// Round 4
// 106.884 us; speedup vs baseline: 1.0504x; 1.0297x over previous
//
#include <hip/hip_runtime.h>
#include <math.h>

// S4 diagonal SSM: B=2, L=2048, H=512, N=64. Two-level chunks: micro T=32,
// 4 micros/macro, 16 macros. TWO kernels (was 4):
//   K1 k_ploc: micro local states + in-block 4-wide macro scan (LDS) ->
//              Ploc[b][c][n][h] = state at end of micro c from zero at macro start.
//   K2 k_y:    carry = Ploc[c-1] + ApT^j * sum_{m'<m} ApT4^{m-1-m'} * A[m'] (<=16
//              L2-hot row loads), then exact recurrence re-run + C.x dot + D.u.
// R10 theory: R0/R1/R3 (3 very different structures, >=2x work delta) all land
// 107-112us while ideal kernel sum is ~17us -> fixed overhead dominates:
// ~46us workspace re-poison + ~10us per launch boundary. Lever = launch count.
// Coeffs recomputed per-thread (expm1 poly, dA<=1e-3); tables/scan kernels gone.
// XCD homing: bid&7 = h[8:6] in BOTH kernels -> u (1MB/XCD) + Ploc (2MB/XCD)
// stay L2-resident across the boundary. No inter-block sync anywhere.
// Lessons: (R4) coop grid.sync ~70us -- never; (R7) occupancy alone no effect;
// (R8/R9) instruction-count cuts alone no effect -> overhead-bound.

#define BATCH   2
#define SEQLEN  2048
#define DMODEL  512
#define DSTATE  64
#define TMICRO  32
#define NMICRO  64      // micro-chunks per batch
#define MPM     4       // micros per macro
#define NMACRO  16

__device__ __forceinline__ float A_cont(int n) {
    // A[n] = (1 + (n+1)/64)^(-1/2)
    return rsqrtf(1.0f + (float)(n + 1) * (1.0f / 64.0f));
}

// expm1 for |x| <= ~1e-3: x + x^2/2 + x^3/6  (abs err ~x^4/24 ~ 4e-14)
__device__ __forceinline__ float expm1_small(float x) {
    return fmaf(fmaf(0.16666667f, x, 0.5f), x * x, x);
}

// ---------------- K1: micro local states + in-block macro scan ----------------
// grid 1024 = hh(8, =bid&7 XCD home) x [b(2) x q2(4) x mc(16)]
// block 256 = hl(16) x ng(4) x cm(4, wave id)
__global__ __launch_bounds__(256) void k_ploc(const float* __restrict__ u,
                                              const float* __restrict__ B_re,
                                              const float* __restrict__ log_dt,
                                              float* __restrict__ Ploc) {
    __shared__ float sm[MPM][4][16][17];           // [cm][ng][nn][hl], padded
    int bid = (int)blockIdx.x;
    int hh = bid & 7;                              // h[8:6] -> XCD home
    int k  = bid >> 3;                             // 0..127
    int b  = k >> 6;
    int q2 = (k >> 4) & 3;                         // h[5:4]
    int mc = k & 15;                               // macro index
    int tx = (int)threadIdx.x;
    int hl = tx & 15;
    int ng = (tx >> 4) & 3;
    int cm = tx >> 6;                              // micro-in-macro (= wave id)
    int h  = (hh << 6) | (q2 << 4) | hl;
    int c  = mc * MPM + cm;
    int n0 = ng * 16;

    float delta = expf(log_dt[h]);
    float Ad[16], Bd[16], Ap[16], x[16];
    #pragma unroll
    for (int nn = 0; nn < 16; ++nn) {
        int n = n0 + nn;
        float dA = delta * A_cont(n);
        float em = expm1_small(dA);
        Ad[nn] = 1.0f + em;
        Bd[nn] = em * B_re[n] * delta;
        float p = Ad[nn];
        p = p * p; p = p * p; p = p * p; p = p * p; p = p * p;   // Ad^32
        Ap[nn] = p;
        x[nn] = 0.0f;
    }
    const float* up = u + ((size_t)(b * SEQLEN + c * TMICRO)) * DMODEL + h;
    #pragma unroll 8
    for (int s = 0; s < TMICRO; ++s) {
        float uv = up[(size_t)s * DMODEL];         // coalesced in h
        #pragma unroll
        for (int nn = 0; nn < 16; ++nn)
            x[nn] = fmaf(Ad[nn], x[nn], Bd[nn] * uv);
    }
    // stash micro aggregates, then 4-wide macro prefix (weights Ap^(cm-j))
    #pragma unroll
    for (int nn = 0; nn < 16; ++nn) sm[cm][ng][nn][hl] = x[nn];
    __syncthreads();
    #pragma unroll
    for (int nn = 0; nn < 16; ++nn) {
        float w = Ap[nn];
        float p = x[nn];
        for (int j = cm - 1; j >= 0; --j) {        // cm uniform per wave
            p = fmaf(w, sm[j][ng][nn][hl], p);
            w *= Ap[nn];
        }
        x[nn] = p;
    }
    float* pp = Ploc + ((size_t)((b * NMICRO + c) * DSTATE + n0)) * DMODEL + h;
    #pragma unroll
    for (int nn = 0; nn < 16; ++nn) pp[(size_t)nn * DMODEL] = x[nn];
}

// ---------------- K2: carry reconstruction + recurrence + y ----------------
// grid 1024 = hh(8, =bid&7) x [b(2) x c(64)]
// block 256 = hl(16) x ng(4) x hm2(4); lane bits: hl=0-3, ng=4-5
__global__ __launch_bounds__(256) void k_y(const float* __restrict__ u,
                                           const float* __restrict__ B_re,
                                           const float* __restrict__ C_re,
                                           const float* __restrict__ log_dt,
                                           const float* __restrict__ Dp,
                                           const float* __restrict__ Ploc,
                                           float* __restrict__ out) {
    int bid = (int)blockIdx.x;
    int hh = bid & 7;                              // same XCD home as K1
    int k  = bid >> 3;
    int b  = k >> 6;
    int c  = k & 63;
    int tx = (int)threadIdx.x;
    int hl = tx & 15;
    int ng = (tx >> 4) & 3;
    int hm2 = tx >> 6;
    int h  = (hh << 6) | (hm2 << 4) | hl;
    int n0 = ng * 16;
    int m = c >> 2, j = c & 3;                     // macro idx, micro-in-macro

    float delta = expf(log_dt[h]);
    float Dv = Dp[h];
    float Ad[16], Bd[16], Cw[16], x[16];
    #pragma unroll
    for (int nn = 0; nn < 16; ++nn) {
        int n = n0 + nn;
        float dA = delta * A_cont(n);
        float em = expm1_small(dA);
        Ad[nn] = 1.0f + em;
        Bd[nn] = em * B_re[n] * delta;
        Cw[nn] = C_re[n];
        x[nn] = 0.0f;
    }
    // carry entering micro c: Ploc[c-1] (if j>0) + ApT^j * sum ApT4^... * A[m']
    if (j > 0) {
        const float* pp = Ploc + ((size_t)((b * NMICRO + (c - 1)) * DSTATE + n0)) * DMODEL + h;
        #pragma unroll
        for (int nn = 0; nn < 16; ++nn) x[nn] = pp[(size_t)nn * DMODEL];
    }
    if (m > 0) {
        float wj[16], w4[16];
        #pragma unroll
        for (int nn = 0; nn < 16; ++nn) {
            float p = Ad[nn];
            p = p * p; p = p * p; p = p * p; p = p * p; p = p * p;  // ApT = Ad^32
            float t2 = p * p;                      // ApT^2
            float w = 1.0f;
            if (j & 1) w = p;                      // j block-uniform
            if (j & 2) w *= t2;
            wj[nn] = w;                            // ApT^j
            w4[nn] = t2 * t2;                      // ApT^4 (macro decay)
        }
        for (int mp = m - 1; mp >= 0; --mp) {
            const float* ap = Ploc + ((size_t)((b * NMICRO + (mp * 4 + 3)) * DSTATE + n0)) * DMODEL + h;
            #pragma unroll
            for (int nn = 0; nn < 16; ++nn) {
                x[nn] = fmaf(wj[nn], ap[(size_t)nn * DMODEL], x[nn]);
                wj[nn] *= w4[nn];
            }
        }
    }
    const float* up = u   + ((size_t)(b * SEQLEN + c * TMICRO)) * DMODEL + h;
    float*       op = out + ((size_t)(b * SEQLEN + c * TMICRO)) * DMODEL + h;
    int store_lane = ((tx & 48) == 0);             // lanes 0-15 of each wave

    #pragma unroll 4
    for (int t = 0; t < TMICRO; ++t) {
        float uv = up[(size_t)t * DMODEL];
        #pragma unroll
        for (int nn = 0; nn < 16; ++nn)
            x[nn] = fmaf(Ad[nn], x[nn], Bd[nn] * uv);
        float a0 = 0.0f, a1 = 0.0f, a2 = 0.0f, a3 = 0.0f;
        #pragma unroll
        for (int nn = 0; nn < 16; nn += 4) {
            a0 = fmaf(Cw[nn + 0], x[nn + 0], a0);
            a1 = fmaf(Cw[nn + 1], x[nn + 1], a1);
            a2 = fmaf(Cw[nn + 2], x[nn + 2], a2);
            a3 = fmaf(Cw[nn + 3], x[nn + 3], a3);
        }
        float acc = (a0 + a1) + (a2 + a3);
        acc += __shfl_xor(acc, 16);                // combine ng pairs
        acc += __shfl_xor(acc, 32);                // full 64-n sum
        if (store_lane)
            __builtin_nontemporal_store(fmaf(Dv, uv, acc), &op[(size_t)t * DMODEL]);
    }
}

extern "C" void kernel_launch(void* const* d_in, const int* in_sizes, int n_in,
                              void* d_out, int out_size, void* d_ws, size_t ws_size,
                              hipStream_t stream) {
    const float* u      = (const float*)d_in[0];
    const float* B_re   = (const float*)d_in[1];
    const float* C_re   = (const float*)d_in[2];
    const float* log_dt = (const float*)d_in[3];
    const float* D      = (const float*)d_in[4];
    float* out = (float*)d_out;
    float* ws  = (float*)d_ws;

    float* Ploc = ws;                              // 2*64*64*512 floats = 16 MB

    k_ploc<<<1024, 256, 0, stream>>>(u, B_re, log_dt, Ploc);
    k_y   <<<1024, 256, 0, stream>>>(u, B_re, C_re, log_dt, D, Ploc, out);
}